// Round 1
// baseline (833.318 us; speedup 1.0000x reference)
//
#include <hip/hip_runtime.h>

// Problem constants: B=4, C=64 (in & out for deform), H=W=256.
#define BB 4
#define CC 64
#define HH 256
#define WW 256
#define HWHW 65536

// ---------------------------------------------------------------------------
// Prep: transpose weights into scalar-load-friendly layouts in d_ws.
//   wA[c][k][o18]  from offset_w[o][c][ky][kx]  (only o<18 needed: ow[:, :18])
//   wB[k][c][o64]  from dc_w[o][c][ky][kx]
// ---------------------------------------------------------------------------
__global__ void prep_weights(const float* __restrict__ offset_w,
                             const float* __restrict__ dc_w,
                             float* __restrict__ wA,
                             float* __restrict__ wB) {
    int idx = blockIdx.x * 256 + threadIdx.x;
    const int NA = CC * 9 * 18;       // 10368
    const int NB = 9 * CC * CC;       // 36864
    if (idx < NA) {
        int c = idx / (9 * 18);
        int k = (idx / 18) % 9;
        int o = idx % 18;
        wA[idx] = offset_w[(o * CC + c) * 9 + k];
    }
    int j = idx - NA;
    if (j >= 0 && j < NB) {
        int k = j / (CC * CC);
        int c = (j / CC) % CC;
        int o = j % CC;
        wB[j] = dc_w[(o * CC + c) * 9 + k];
    }
}

// ---------------------------------------------------------------------------
// Offset conv: 3x3, pad 1, 64 -> 18 channels. One thread per pixel,
// one block per (b, y) row. Weights via wave-uniform (scalar) loads.
// ---------------------------------------------------------------------------
__global__ __launch_bounds__(256) void offset_conv(
    const float* __restrict__ blur, const float* __restrict__ wA,
    const float* __restrict__ ob, float* __restrict__ offout) {
    const int x = threadIdx.x;
    const int y = blockIdx.x & (HH - 1);
    const int b = blockIdx.x >> 8;

    float acc[18];
#pragma unroll
    for (int o = 0; o < 18; ++o) acc[o] = ob[o];

    const float* img = blur + (size_t)b * CC * HWHW;
    for (int c = 0; c < CC; ++c) {
        const float* pl = img + c * HWHW;
        float s[9];
#pragma unroll
        for (int dy = 0; dy < 3; ++dy) {
            int yy = y + dy - 1;
            bool vy = (yy >= 0) && (yy < HH);
#pragma unroll
            for (int dx = 0; dx < 3; ++dx) {
                int xx = x + dx - 1;
                bool v = vy && (xx >= 0) && (xx < WW);
                int yc = min(max(yy, 0), HH - 1);
                int xc = min(max(xx, 0), WW - 1);
                s[dy * 3 + dx] = v ? pl[yc * WW + xc] : 0.0f;
            }
        }
        const float* wp = wA + c * 9 * 18;
#pragma unroll
        for (int k = 0; k < 9; ++k) {
            float sv = s[k];
#pragma unroll
            for (int o = 0; o < 18; ++o)
                acc[o] = fmaf(sv, wp[k * 18 + o], acc[o]);
        }
    }

    float* op = offout + ((size_t)b * 18) * HWHW + y * WW + x;
#pragma unroll
    for (int o = 0; o < 18; ++o) op[(size_t)o * HWHW] = acc[o];
}

// ---------------------------------------------------------------------------
// Deformable conv: per pixel, 9 bilinear-sampled taps, 64x64 mat-vec each.
// Validity folded into corner weights; indices clamped (branch-free loads).
// ---------------------------------------------------------------------------
__global__ __launch_bounds__(256) void deform_conv(
    const float* __restrict__ content, const float* __restrict__ offs,
    const float* __restrict__ wB, const float* __restrict__ bias,
    float* __restrict__ out) {
    const int x = threadIdx.x;
    const int y = blockIdx.x & (HH - 1);
    const int b = blockIdx.x >> 8;

    float acc[CC];
#pragma unroll
    for (int o = 0; o < CC; ++o) acc[o] = bias[o];

    const float* img = content + (size_t)b * CC * HWHW;
    const float* offp = offs + ((size_t)b * 18) * HWHW + y * WW + x;

    for (int k = 0; k < 9; ++k) {
        const int ky = k / 3, kx = k % 3;
        const float offy = offp[(size_t)(2 * k) * HWHW];
        const float offx = offp[(size_t)(2 * k + 1) * HWHW];
        const float py = (float)(y + ky - 1) + offy;
        const float px = (float)(x + kx - 1) + offx;
        const float y0f = floorf(py), x0f = floorf(px);
        const float wy = py - y0f, wx = px - x0f;
        const int y0 = (int)y0f, x0 = (int)x0f;

        float w00 = (1.0f - wy) * (1.0f - wx);
        float w01 = (1.0f - wy) * wx;
        float w10 = wy * (1.0f - wx);
        float w11 = wy * wx;
        const bool vy0 = (y0 >= 0) && (y0 < HH);
        const bool vy1 = (y0 + 1 >= 0) && (y0 + 1 < HH);
        const bool vx0 = (x0 >= 0) && (x0 < WW);
        const bool vx1 = (x0 + 1 >= 0) && (x0 + 1 < WW);
        if (!(vy0 && vx0)) w00 = 0.0f;
        if (!(vy0 && vx1)) w01 = 0.0f;
        if (!(vy1 && vx0)) w10 = 0.0f;
        if (!(vy1 && vx1)) w11 = 0.0f;

        const int y0c = min(max(y0, 0), HH - 1);
        const int y1c = min(max(y0 + 1, 0), HH - 1);
        const int x0c = min(max(x0, 0), WW - 1);
        const int x1c = min(max(x0 + 1, 0), WW - 1);

        const float* p00 = img + y0c * WW + x0c;
        const float* p01 = img + y0c * WW + x1c;
        const float* p10 = img + y1c * WW + x0c;
        const float* p11 = img + y1c * WW + x1c;

        const float* wkp = wB + (size_t)k * CC * CC;
        for (int c = 0; c < CC; ++c) {
            const float v00 = p00[(size_t)c * HWHW];
            const float v01 = p01[(size_t)c * HWHW];
            const float v10 = p10[(size_t)c * HWHW];
            const float v11 = p11[(size_t)c * HWHW];
            const float samp = w00 * v00 + w01 * v01 + w10 * v10 + w11 * v11;
            const float* wc = wkp + c * CC;
#pragma unroll
            for (int o = 0; o < CC; ++o)
                acc[o] = fmaf(samp, wc[o], acc[o]);
        }
    }

    float* op = out + (size_t)b * CC * HWHW + y * WW + x;
#pragma unroll
    for (int o = 0; o < CC; ++o) op[(size_t)o * HWHW] = acc[o];
}

// ---------------------------------------------------------------------------
extern "C" void kernel_launch(void* const* d_in, const int* in_sizes, int n_in,
                              void* d_out, int out_size, void* d_ws, size_t ws_size,
                              hipStream_t stream) {
    const float* content  = (const float*)d_in[0];
    const float* blur     = (const float*)d_in[1];
    const float* offset_w = (const float*)d_in[2];
    const float* offset_b = (const float*)d_in[3];
    const float* dc_w     = (const float*)d_in[4];
    const float* dc_b     = (const float*)d_in[5];

    float* out0    = (float*)d_out;                                // (4,64,256,256)
    float* off_out = out0 + (size_t)BB * CC * HWHW;                // (4,18,256,256)

    float* wA = (float*)d_ws;                 // 10368 floats
    float* wB = wA + CC * 9 * 18;             // 36864 floats

    const int NPREP = CC * 9 * 18 + 9 * CC * CC;  // 47232
    prep_weights<<<(NPREP + 255) / 256, 256, 0, stream>>>(offset_w, dc_w, wA, wB);
    offset_conv<<<BB * HH, 256, 0, stream>>>(blur, wA, offset_b, off_out);
    deform_conv<<<BB * HH, 256, 0, stream>>>(content, off_out, wB, dc_b, out0);
}

// Round 2
// 658.081 us; speedup vs baseline: 1.2663x; 1.2663x over previous
//
#include <hip/hip_runtime.h>

// Problem constants: B=4, C=64 (in & out for deform), H=W=256.
#define BB 4
#define CC 64
#define HH 256
#define WW 256
#define HWHW 65536

// ---------------------------------------------------------------------------
// Prep: transpose weights into scalar-load-friendly layouts in d_ws.
//   wA[c][k][o18]  from offset_w[o][c][ky][kx]  (only o<18 needed: ow[:, :18])
//   wB[c][k][o64]  from dc_w[o][c][ky][kx]   (c-major so each c-iter's 576
//                                             weights are contiguous)
// ---------------------------------------------------------------------------
__global__ void prep_weights(const float* __restrict__ offset_w,
                             const float* __restrict__ dc_w,
                             float* __restrict__ wA,
                             float* __restrict__ wB) {
    int idx = blockIdx.x * 256 + threadIdx.x;
    const int NA = CC * 9 * 18;       // 10368
    const int NB = 9 * CC * CC;       // 36864
    if (idx < NA) {
        int c = idx / (9 * 18);
        int k = (idx / 18) % 9;
        int o = idx % 18;
        wA[idx] = offset_w[(o * CC + c) * 9 + k];
    }
    int j = idx - NA;
    if (j >= 0 && j < NB) {
        int c = j / (9 * CC);
        int k = (j / CC) % 9;
        int o = j % CC;
        wB[j] = dc_w[(o * CC + c) * 9 + k];
    }
}

// ---------------------------------------------------------------------------
// Offset conv: 3x3, pad 1, 64 -> 18 channels. One thread per pixel,
// one block per (b, y) row. Row bases / masks hoisted out of the c loop.
// ---------------------------------------------------------------------------
__global__ __launch_bounds__(256) void offset_conv(
    const float* __restrict__ blur, const float* __restrict__ wA,
    const float* __restrict__ ob, float* __restrict__ offout) {
    const int x = threadIdx.x;
    const int y = blockIdx.x & (HH - 1);
    const int b = blockIdx.x >> 8;

    // Hoisted addressing: clamped row bases, clamped col indices, validity.
    int rb[3], cx[3];
    float m[9];
#pragma unroll
    for (int dy = 0; dy < 3; ++dy) {
        int yy = y + dy - 1;
        rb[dy] = min(max(yy, 0), HH - 1) * WW;
        bool vy = (yy >= 0) && (yy < HH);
#pragma unroll
        for (int dx = 0; dx < 3; ++dx) {
            int xx = x + dx - 1;
            bool v = vy && (xx >= 0) && (xx < WW);
            m[dy * 3 + dx] = v ? 1.0f : 0.0f;
        }
    }
#pragma unroll
    for (int dx = 0; dx < 3; ++dx) cx[dx] = min(max(x + dx - 1, 0), WW - 1);

    float acc[18];
#pragma unroll
    for (int o = 0; o < 18; ++o) acc[o] = ob[o];

    const float* img = blur + (size_t)b * CC * HWHW;
    for (int c = 0; c < CC; ++c) {
        const float* pl = img + c * HWHW;
        float s[9];
#pragma unroll
        for (int dy = 0; dy < 3; ++dy)
#pragma unroll
            for (int dx = 0; dx < 3; ++dx)
                s[dy * 3 + dx] = pl[rb[dy] + cx[dx]] * m[dy * 3 + dx];

        const float* wp = wA + c * 9 * 18;
#pragma unroll
        for (int k = 0; k < 9; ++k) {
            float sv = s[k];
#pragma unroll
            for (int o = 0; o < 18; ++o)
                acc[o] = fmaf(sv, wp[k * 18 + o], acc[o]);
        }
    }

    float* op = offout + ((size_t)b * 18) * HWHW + y * WW + x;
#pragma unroll
    for (int o = 0; o < 18; ++o) op[(size_t)o * HWHW] = acc[o];
}

// ---------------------------------------------------------------------------
// Deformable conv, c-OUTER / k-inner: per c-iteration a block touches ~5 rows
// of ONE channel plane (~5 KB), reused by all 9 taps (L1) and neighbor blocks
// (L2) — kills the 9x HBM re-fetch of the k-outer order.
// Per-k bilinear weights + compact indices hoisted out of the c loop.
// ---------------------------------------------------------------------------
__global__ __launch_bounds__(256) void deform_conv(
    const float* __restrict__ content, const float* __restrict__ offs,
    const float* __restrict__ wB, const float* __restrict__ bias,
    float* __restrict__ out) {
    const int x = threadIdx.x;
    const int y = blockIdx.x & (HH - 1);
    const int b = blockIdx.x >> 8;

    const float* offp = offs + ((size_t)b * 18) * HWHW + y * WW + x;

    // Precompute per-tap bilinear corner weights (validity folded) and
    // compact indices: i00 (clamped base), dx1 in {0,1}, dyW in {0,WW}.
    float w00[9], w01[9], w10[9], w11[9];
    int i00[9], dx1[9], dyW[9];
#pragma unroll
    for (int k = 0; k < 9; ++k) {
        const int ky = k / 3, kx = k % 3;
        const float offy = offp[(size_t)(2 * k) * HWHW];
        const float offx = offp[(size_t)(2 * k + 1) * HWHW];
        const float py = (float)(y + ky - 1) + offy;
        const float px = (float)(x + kx - 1) + offx;
        const float y0f = floorf(py), x0f = floorf(px);
        const float wy = py - y0f, wx = px - x0f;
        const int y0 = (int)y0f, x0 = (int)x0f;

        float a00 = (1.0f - wy) * (1.0f - wx);
        float a01 = (1.0f - wy) * wx;
        float a10 = wy * (1.0f - wx);
        float a11 = wy * wx;
        const bool vy0 = (y0 >= 0) && (y0 < HH);
        const bool vy1 = (y0 + 1 >= 0) && (y0 + 1 < HH);
        const bool vx0 = (x0 >= 0) && (x0 < WW);
        const bool vx1 = (x0 + 1 >= 0) && (x0 + 1 < WW);
        w00[k] = (vy0 && vx0) ? a00 : 0.0f;
        w01[k] = (vy0 && vx1) ? a01 : 0.0f;
        w10[k] = (vy1 && vx0) ? a10 : 0.0f;
        w11[k] = (vy1 && vx1) ? a11 : 0.0f;

        const int y0c = min(max(y0, 0), HH - 1);
        const int y1c = min(max(y0 + 1, 0), HH - 1);
        const int x0c = min(max(x0, 0), WW - 1);
        const int x1c = min(max(x0 + 1, 0), WW - 1);
        i00[k] = y0c * WW + x0c;
        dx1[k] = x1c - x0c;          // 0 or 1
        dyW[k] = (y1c - y0c) * WW;   // 0 or WW
    }

    float acc[CC];
#pragma unroll
    for (int o = 0; o < CC; ++o) acc[o] = bias[o];

    const float* img = content + (size_t)b * CC * HWHW;

    for (int c = 0; c < CC; ++c) {
        const float* pl = img + (size_t)c * HWHW;
        float samp[9];
#pragma unroll
        for (int k = 0; k < 9; ++k) {
            const float v00 = pl[i00[k]];
            const float v01 = pl[i00[k] + dx1[k]];
            const float v10 = pl[i00[k] + dyW[k]];
            const float v11 = pl[i00[k] + dyW[k] + dx1[k]];
            samp[k] = w00[k] * v00 + w01[k] * v01 + w10[k] * v10 + w11[k] * v11;
        }
        const float* wc = wB + (size_t)c * 9 * CC;   // 576 contiguous floats
#pragma unroll
        for (int k = 0; k < 9; ++k) {
            const float sv = samp[k];
#pragma unroll
            for (int o = 0; o < CC; ++o)
                acc[o] = fmaf(sv, wc[k * CC + o], acc[o]);
        }
    }

    float* op = out + (size_t)b * CC * HWHW + y * WW + x;
#pragma unroll
    for (int o = 0; o < CC; ++o) op[(size_t)o * HWHW] = acc[o];
}

// ---------------------------------------------------------------------------
extern "C" void kernel_launch(void* const* d_in, const int* in_sizes, int n_in,
                              void* d_out, int out_size, void* d_ws, size_t ws_size,
                              hipStream_t stream) {
    const float* content  = (const float*)d_in[0];
    const float* blur     = (const float*)d_in[1];
    const float* offset_w = (const float*)d_in[2];
    const float* offset_b = (const float*)d_in[3];
    const float* dc_w     = (const float*)d_in[4];
    const float* dc_b     = (const float*)d_in[5];

    float* out0    = (float*)d_out;                                // (4,64,256,256)
    float* off_out = out0 + (size_t)BB * CC * HWHW;                // (4,18,256,256)

    float* wA = (float*)d_ws;                 // 10368 floats
    float* wB = wA + CC * 9 * 18;             // 36864 floats

    const int NPREP = CC * 9 * 18 + 9 * CC * CC;  // 47232
    prep_weights<<<(NPREP + 255) / 256, 256, 0, stream>>>(offset_w, dc_w, wA, wB);
    offset_conv<<<BB * HH, 256, 0, stream>>>(blur, wA, offset_b, off_out);
    deform_conv<<<BB * HH, 256, 0, stream>>>(content, off_out, wB, dc_b, out0);
}

// Round 3
// 616.502 us; speedup vs baseline: 1.3517x; 1.0674x over previous
//
#include <hip/hip_runtime.h>

// Problem constants: B=4, C=64 (in & out for deform), H=W=256.
#define BB 4
#define CC 64
#define HH 256
#define WW 256
#define HWHW 65536

typedef __bf16 bf16x8 __attribute__((ext_vector_type(8)));
typedef float f32x16 __attribute__((ext_vector_type(16)));
typedef unsigned int uint4v __attribute__((ext_vector_type(4)));
typedef unsigned int uint2v __attribute__((ext_vector_type(2)));

__device__ __forceinline__ unsigned short f32_to_bf16(float s) {
    unsigned int xi = __builtin_bit_cast(unsigned int, s);
    unsigned int r = (xi + 0x7fffu + ((xi >> 16) & 1u)) >> 16;  // RNE
    return (unsigned short)r;
}

// ---------------------------------------------------------------------------
// Prep:
//   wA[c][k][o18]  fp32, from offset_w[o][c][ky][kx]  (offset conv weights)
//   WB2: bf16 deform weights in MFMA-ready LDS layout:
//        [chunk(4)][kslot(18)][n(64)][j(8)] where k_local = kslot*8+j,
//        c = chunk*16 + k_local/9, tap = k_local%9, value = dc_w[n][c][tap]
// ---------------------------------------------------------------------------
__global__ void prep_weights(const float* __restrict__ offset_w,
                             const float* __restrict__ dc_w,
                             float* __restrict__ wA,
                             unsigned short* __restrict__ WB2) {
    int idx = blockIdx.x * 256 + threadIdx.x;
    const int NA = CC * 9 * 18;            // 10368
    const int NB = 4 * 18 * 64 * 8;        // 36864
    if (idx < NA) {
        int c = idx / (9 * 18);
        int k = (idx / 18) % 9;
        int o = idx % 18;
        wA[idx] = offset_w[(o * CC + c) * 9 + k];
    }
    int j = idx - NA;
    if (j >= 0 && j < NB) {
        int chunk = j / 9216;              // 9216 = 18*64*8
        int rem = j - chunk * 9216;
        int kslot = rem >> 9;              // /(64*8)
        int n = (rem >> 3) & 63;
        int jj = rem & 7;
        int k_local = kslot * 8 + jj;      // < 144
        int c_local = k_local / 9;
        int tap = k_local - c_local * 9;
        int c = chunk * 16 + c_local;
        WB2[j] = f32_to_bf16(dc_w[(n * CC + c) * 9 + tap]);
    }
}

// ---------------------------------------------------------------------------
// Offset conv (unchanged, fp32-exact): 3x3, pad 1, 64 -> 18 channels.
// ---------------------------------------------------------------------------
__global__ __launch_bounds__(256) void offset_conv(
    const float* __restrict__ blur, const float* __restrict__ wA,
    const float* __restrict__ ob, float* __restrict__ offout) {
    const int x = threadIdx.x;
    const int y = blockIdx.x & (HH - 1);
    const int b = blockIdx.x >> 8;

    int rb[3], cx[3];
    float m[9];
#pragma unroll
    for (int dy = 0; dy < 3; ++dy) {
        int yy = y + dy - 1;
        rb[dy] = min(max(yy, 0), HH - 1) * WW;
        bool vy = (yy >= 0) && (yy < HH);
#pragma unroll
        for (int dx = 0; dx < 3; ++dx) {
            int xx = x + dx - 1;
            bool v = vy && (xx >= 0) && (xx < WW);
            m[dy * 3 + dx] = v ? 1.0f : 0.0f;
        }
    }
#pragma unroll
    for (int dx = 0; dx < 3; ++dx) cx[dx] = min(max(x + dx - 1, 0), WW - 1);

    float acc[18];
#pragma unroll
    for (int o = 0; o < 18; ++o) acc[o] = ob[o];

    const float* img = blur + (size_t)b * CC * HWHW;
    for (int c = 0; c < CC; ++c) {
        const float* pl = img + c * HWHW;
        float s[9];
#pragma unroll
        for (int dy = 0; dy < 3; ++dy)
#pragma unroll
            for (int dx = 0; dx < 3; ++dx)
                s[dy * 3 + dx] = pl[rb[dy] + cx[dx]] * m[dy * 3 + dx];

        const float* wp = wA + c * 9 * 18;
#pragma unroll
        for (int k = 0; k < 9; ++k) {
            float sv = s[k];
#pragma unroll
            for (int o = 0; o < 18; ++o)
                acc[o] = fmaf(sv, wp[k * 18 + o], acc[o]);
        }
    }

    float* op = offout + ((size_t)b * 18) * HWHW + y * WW + x;
#pragma unroll
    for (int o = 0; o < 18; ++o) op[(size_t)o * HWHW] = acc[o];
}

// ---------------------------------------------------------------------------
// Deformable conv as implicit GEMM on MFMA.
// Block = 256 thr = 4 waves, tile = 64 pixels (one 64-px x-segment) x 64 outs.
// K = 576 (= c*9+tap), chunked 4 x 144.
// Producer: thread t -> pixel t&63, channel-group t>>6 (4 ch x 9 taps = 36
//   bf16 samples/chunk) -> LDS samp[kslot][px][8] (b128-aligned, bank-even).
// Consumer: wave w computes 32x32 quadrant via 9x mfma_f32_32x32x16_bf16.
// Epilogue: LDS transpose (stride 65) -> coalesced stores + bias.
// ---------------------------------------------------------------------------
__global__ __launch_bounds__(256) void deform_mfma(
    const float* __restrict__ content, const float* __restrict__ offs,
    const unsigned short* __restrict__ WB2, const float* __restrict__ bias,
    float* __restrict__ out) {
    __shared__ char ldsbuf[36864];
    unsigned int* sampU = (unsigned int*)ldsbuf;            // [18][64][4] uints
    unsigned int* wU    = (unsigned int*)(ldsbuf + 18432);  // [18][64][4] uints
    float* ldsOut       = (float*)ldsbuf;                   // [64][65] (epilogue alias)

    const int t = threadIdx.x;
    const int px = t & 63;
    const int cg = t >> 6;                 // wave id == channel group
    const int blk = blockIdx.x;
    const int xseg = blk & 3;
    const int y = (blk >> 2) & (HH - 1);
    const int b = blk >> 10;
    const int x = xseg * 64 + px;

    // ---- per-pixel bilinear state for 9 taps (recomputed by 4 thr/px) ----
    const float* offp = offs + ((size_t)b * 18) * HWHW + y * WW + x;
    float w00[9], w01[9], w10[9], w11[9];
    int i00[9], dx1[9], dyW[9];
#pragma unroll
    for (int k = 0; k < 9; ++k) {
        const int ky = k / 3, kx = k % 3;
        const float offy = offp[(size_t)(2 * k) * HWHW];
        const float offx = offp[(size_t)(2 * k + 1) * HWHW];
        const float py = (float)(y + ky - 1) + offy;
        const float pxf = (float)(x + kx - 1) + offx;
        const float y0f = floorf(py), x0f = floorf(pxf);
        const float wy = py - y0f, wx = pxf - x0f;
        const int y0 = (int)y0f, x0 = (int)x0f;

        float a00 = (1.0f - wy) * (1.0f - wx);
        float a01 = (1.0f - wy) * wx;
        float a10 = wy * (1.0f - wx);
        float a11 = wy * wx;
        const bool vy0 = (y0 >= 0) && (y0 < HH);
        const bool vy1 = (y0 + 1 >= 0) && (y0 + 1 < HH);
        const bool vx0 = (x0 >= 0) && (x0 < WW);
        const bool vx1 = (x0 + 1 >= 0) && (x0 + 1 < WW);
        w00[k] = (vy0 && vx0) ? a00 : 0.0f;
        w01[k] = (vy0 && vx1) ? a01 : 0.0f;
        w10[k] = (vy1 && vx0) ? a10 : 0.0f;
        w11[k] = (vy1 && vx1) ? a11 : 0.0f;

        const int y0c = min(max(y0, 0), HH - 1);
        const int y1c = min(max(y0 + 1, 0), HH - 1);
        const int x0c = min(max(x0, 0), WW - 1);
        const int x1c = min(max(x0 + 1, 0), WW - 1);
        i00[k] = y0c * WW + x0c;
        dx1[k] = x1c - x0c;          // 0 or 1
        dyW[k] = (y1c - y0c) * WW;   // 0 or WW
    }

    const float* img = content + (size_t)b * CC * HWHW;

    f32x16 acc = {0, 0, 0, 0, 0, 0, 0, 0, 0, 0, 0, 0, 0, 0, 0, 0};

    const int lane = t & 63;
    const int half = lane >> 5;
    const int l31 = lane & 31;
    const int px_i = ((cg >> 1) * 32) + l31;   // A-frag pixel row
    const int n_i = ((cg & 1) * 32) + l31;     // B-frag out-channel col

    for (int chunk = 0; chunk < 4; ++chunk) {
        // ---- stage weight chunk global -> LDS (1152 x 16B) ----
        {
            const uint4v* src = (const uint4v*)(WB2 + (size_t)chunk * 9216);
            uint4v* dst = (uint4v*)wU;
            for (int j = t; j < 1152; j += 256) dst[j] = src[j];
        }

        // ---- produce 36 bf16 samples (4 ch x 9 taps), packed in 18 uints ----
        unsigned int pk[18];
        const int c0 = chunk * 16 + cg * 4;
#pragma unroll
        for (int i = 0; i < 4; ++i) {
            const float* pl = img + (size_t)(c0 + i) * HWHW;
#pragma unroll
            for (int tap = 0; tap < 9; ++tap) {
                const float v00 = pl[i00[tap]];
                const float v01 = pl[i00[tap] + dx1[tap]];
                const float v10 = pl[i00[tap] + dyW[tap]];
                const float v11 = pl[i00[tap] + dyW[tap] + dx1[tap]];
                const float s = w00[tap] * v00 + w01[tap] * v01 +
                                w10[tap] * v10 + w11[tap] * v11;
                const unsigned int u = f32_to_bf16(s);
                const int idx = i * 9 + tap;
                if (idx & 1) pk[idx >> 1] |= u << 16;
                else         pk[idx >> 1] = u;
            }
        }

        // ---- write samples to LDS: k_local = cg*36 + (i*9+tap) ----
        {
            const int s0 = (cg * 36) >> 3;     // starting kslot
            if ((cg & 1) == 0) {
                // 4 full slots + half-slot head of s0+4
#pragma unroll
                for (int g = 0; g < 4; ++g) {
                    uint4v v = {pk[g * 4], pk[g * 4 + 1], pk[g * 4 + 2], pk[g * 4 + 3]};
                    *(uint4v*)&sampU[((s0 + g) * 64 + px) * 4] = v;
                }
                uint2v tl = {pk[16], pk[17]};
                *(uint2v*)&sampU[((s0 + 4) * 64 + px) * 4] = tl;
            } else {
                // half-slot tail of s0, then 4 full slots
                uint2v hd = {pk[0], pk[1]};
                *(uint2v*)&sampU[(s0 * 64 + px) * 4 + 2] = hd;
#pragma unroll
                for (int g = 0; g < 4; ++g) {
                    uint4v v = {pk[2 + g * 4], pk[3 + g * 4], pk[4 + g * 4], pk[5 + g * 4]};
                    *(uint4v*)&sampU[((s0 + 1 + g) * 64 + px) * 4] = v;
                }
            }
        }
        __syncthreads();

        // ---- MFMA: 9 x K16 over this chunk's 144 K-elements ----
        {
            const bf16x8* sampV = (const bf16x8*)sampU;
            const bf16x8* wV = (const bf16x8*)wU;
#pragma unroll
            for (int ks = 0; ks < 9; ++ks) {
                bf16x8 fa = sampV[(ks * 2 + half) * 64 + px_i];
                bf16x8 fb = wV[(ks * 2 + half) * 64 + n_i];
                acc = __builtin_amdgcn_mfma_f32_32x32x16_bf16(fa, fb, acc, 0, 0, 0);
            }
        }
        __syncthreads();
    }

    // ---- epilogue: transpose via LDS (stride 65, bank-clean), coalesced out ----
    {
        const int n_l = (cg & 1) * 32 + l31;
        const int px_base = (cg >> 1) * 32 + 4 * half;
#pragma unroll
        for (int r = 0; r < 16; ++r) {
            const int row = px_base + (r & 3) + 8 * (r >> 2);
            ldsOut[n_l * 65 + row] = acc[r];
        }
    }
    __syncthreads();
    {
        float* base = out + (size_t)b * CC * HWHW + y * WW + xseg * 64;
        for (int i = t; i < 4096; i += 256) {
            const int n = i >> 6;
            const int p = i & 63;
            base[(size_t)n * HWHW + p] = ldsOut[n * 65 + p] + bias[n];
        }
    }
}

// ---------------------------------------------------------------------------
extern "C" void kernel_launch(void* const* d_in, const int* in_sizes, int n_in,
                              void* d_out, int out_size, void* d_ws, size_t ws_size,
                              hipStream_t stream) {
    const float* content  = (const float*)d_in[0];
    const float* blur     = (const float*)d_in[1];
    const float* offset_w = (const float*)d_in[2];
    const float* offset_b = (const float*)d_in[3];
    const float* dc_w     = (const float*)d_in[4];
    const float* dc_b     = (const float*)d_in[5];

    float* out0    = (float*)d_out;                                // (4,64,256,256)
    float* off_out = out0 + (size_t)BB * CC * HWHW;                // (4,18,256,256)

    float* wA = (float*)d_ws;                               // 10368 floats
    unsigned short* WB2 = (unsigned short*)(wA + CC * 9 * 18);  // 36864 bf16

    const int NPREP = CC * 9 * 18 + 4 * 18 * 64 * 8;        // 47232
    prep_weights<<<(NPREP + 255) / 256, 256, 0, stream>>>(offset_w, dc_w, wA, WB2);
    offset_conv<<<BB * HH, 256, 0, stream>>>(blur, wA, offset_b, off_out);
    deform_mfma<<<BB * HH * 4, 256, 0, stream>>>(content, off_out, WB2, dc_b, out0);
}